// Round 6
// baseline (493.087 us; speedup 1.0000x reference)
//
#include <hip/hip_runtime.h>

#define NT 32
#define EPSF 1e-8f

// ================= Gram kernel =================
// G = vecs @ vecs^T, vecs (32, D) fp32 row-major.
// BYTE-IDENTICAL to r7 (fence measured NEUTRAL: 409.99 vs 410.27 — loads were
// already hoisted or latency exposure is not gram's limiter; fence kept,
// harmless). History: r5 verified, SQ_LDS_BANK_CONFLICT=0, no spill.
// Floors (model): HBM 43us, LDS-pipe ~46us, FMA-issue 27us.
#define TILE_COLS 64
#define GR_THREADS 256
#define WAVES_PB 4
#define TILES_PW 8    // cols/wave = 512, cols/block = 2048 -> grid = 1024

__global__ __launch_bounds__(GR_THREADS, 1)
void gram_kernel(const float* __restrict__ vecs, double* __restrict__ Gd, int D)
{
    __shared__ __align__(16) float tile[WAVES_PB][TILE_COLS * 32];
    __shared__ float Gpart[NT * NT];

    const int tid  = threadIdx.x;
    const int wave = tid >> 6;
    const int lane = tid & 63;

    for (int e = tid; e < NT * NT; e += GR_THREADS) Gpart[e] = 0.0f;
    __syncthreads();

    float* my = tile[wave];
    const int swz = lane & 7;

    const int cj = lane >> 4;        // column subgroup 0..3
    const int pi = (lane >> 2) & 3;  // patch rows 8*pi..
    const int pk = lane & 3;         // patch cols 8*pk..

    float acc[8][8];
#pragma unroll
    for (int r = 0; r < 8; r++)
#pragma unroll
        for (int c = 0; c < 8; c++) acc[r][c] = 0.0f;

    const unsigned base0 = (unsigned)blockIdx.x * (WAVES_PB * TILES_PW * TILE_COLS)
                         + (unsigned)wave * (TILES_PW * TILE_COLS) + (unsigned)lane;

    // prefetch tile 0 (SGPR row bases + one 32-bit lane offset)
    float pre[32];
#pragma unroll
    for (int r = 0; r < 32; r++)
        pre[r] = (vecs + (size_t)r * (size_t)D)[base0];

    for (int t = 0; t < TILES_PW; t++) {
        // stage tile t from pre[]: 8 swizzled b128 writes
#pragma unroll
        for (int g = 0; g < 8; g++) {
            float4 w = make_float4(pre[4 * g + 0], pre[4 * g + 1],
                                   pre[4 * g + 2], pre[4 * g + 3]);
            *(float4*)(my + lane * 32 + ((g ^ swz) << 2)) = w;
        }
        // prefetch tile t+1; loads fly during the compute below
        if (t + 1 < TILES_PW) {
            const unsigned off = base0 + (unsigned)(t + 1) * TILE_COLS;
#pragma unroll
            for (int r = 0; r < 32; r++)
                pre[r] = (vecs + (size_t)r * (size_t)D)[off];
        }
        // r7: scheduling fence (measured neutral; kept, harmless)
        asm volatile("" ::: "memory");
        // compute on tile t (per-wave DS ops are in-order; no barrier needed)
#pragma unroll
        for (int jt = 0; jt < 16; jt++) {
            const int j = (jt << 2) + cj;
            const float* col = my + j * 32;
            const int js = j & 7;
            const float4 a0 = *(const float4*)(col + (((2 * pi) ^ js) << 2));
            const float4 a1 = *(const float4*)(col + (((2 * pi + 1) ^ js) << 2));
            const float4 b0 = *(const float4*)(col + (((2 * pk) ^ js) << 2));
            const float4 b1 = *(const float4*)(col + (((2 * pk + 1) ^ js) << 2));
            const float a[8] = {a0.x, a0.y, a0.z, a0.w, a1.x, a1.y, a1.z, a1.w};
            const float b[8] = {b0.x, b0.y, b0.z, b0.w, b1.x, b1.y, b1.z, b1.w};
#pragma unroll
            for (int r = 0; r < 8; r++)
#pragma unroll
                for (int c = 0; c < 8; c++)
                    acc[r][c] = fmaf(a[r], b[c], acc[r][c]);
        }
    }

    // fold the cj column-split (lanes sharing lane&15 share a patch)
#pragma unroll
    for (int r = 0; r < 8; r++)
#pragma unroll
        for (int c = 0; c < 8; c++) {
            float v = acc[r][c];
            v += __shfl_xor(v, 16);
            v += __shfl_xor(v, 32);
            if (lane < 16)
                atomicAdd(&Gpart[(8 * pi + r) * NT + (8 * pk + c)], v);
        }
    __syncthreads();
    for (int e = tid; e < NT * NT; e += GR_THREADS)
        atomicAdd(&Gd[e], (double)Gpart[e]);
}

// ================= Solver kernel =================
// BYTE-IDENTICAL to r6/r7 (measured: passed, absmax 0.0).
// Model estimate: ~650 cy/iter x 250 iters ~= 68-90us. To be confirmed by
// this round's attribution probe (S = budget - G).
template<int CTRL>
__device__ __forceinline__ float dpp0(float x) {  // invalid source lanes -> 0
    return __int_as_float(__builtin_amdgcn_update_dpp(
        0, __float_as_int(x), CTRL, 0xF, 0xF, true));
}
template<int CTRL>
__device__ __forceinline__ float dppk(float oldv, float x) {  // invalid -> oldv
    return __int_as_float(__builtin_amdgcn_update_dpp(
        __float_as_int(oldv), __float_as_int(x), CTRL, 0xF, 0xF, false));
}
__device__ __forceinline__ float rdlane(float x, int l) {
    return __int_as_float(__builtin_amdgcn_readlane(__float_as_int(x), l));
}

// sum over lanes 0..31, uniform (row_shr chain leaves sums at 15 & 31)
__device__ __forceinline__ float bsum32u(float v) {
    v += dpp0<0x111>(v);
    v += dpp0<0x112>(v);
    v += dpp0<0x114>(v);
    v += dpp0<0x118>(v);
    return rdlane(v, 15) + rdlane(v, 31);
}
__device__ __forceinline__ float bmin32u(float v) {
    v = fminf(v, dppk<0x111>(v, v));
    v = fminf(v, dppk<0x112>(v, v));
    v = fminf(v, dppk<0x114>(v, v));
    v = fminf(v, dppk<0x118>(v, v));
    return fminf(rdlane(v, 15), rdlane(v, 31));
}

__global__ __launch_bounds__(64)
void solver_kernel(const double* __restrict__ Gd, float* __restrict__ out)
{
    __shared__ float Gsh[NT * 33];

    const int lane = threadIdx.x;
    const int e = lane & 31;      // element owned (mirrored halves)
    const int h = lane >> 5;      // half: covers k/j in [16h, 16h+16)

    for (int t2 = 0; t2 < 16; t2++) {
        int idx = t2 * 64 + lane;
        Gsh[(idx >> 5) * 33 + (idx & 31)] = (float)Gd[idx];
    }
    __syncthreads();

    // lane holds G[e][16h + k], k = 0..15
    float Grow[16];
#pragma unroll
    for (int k = 0; k < 16; k++)
        Grow[k] = Gsh[e * 33 + 16 * h + k];

    // half-split matvec: y_e = sum_k G[e][k] * x_k  (uniform-mirrored result).
    auto matvec = [&](float x) -> float {
        float a0 = 0.0f, a1 = 0.0f;
#pragma unroll
        for (int s = 0; s < 16; s += 2) {
            a0 = fmaf(Grow[s + 0], __shfl(x, 16 * h + s + 0), a0);
            a1 = fmaf(Grow[s + 1], __shfl(x, 16 * h + s + 1), a1);
        }
        float half = a0 + a1;
        return half + __shfl_xor(half, 32);
    };

    // ---- planar init: argmin over all 496 (a<b) pairs ----
    float bestCost = INFINITY, bestGamma = 0.0f;
    int bestEnc = 0x7FFFFFFF;
    for (int a = 0; a < NT - 1; a++) {
        int b = a + 1 + lane;
        if (b < NT) {
            float v11 = Gsh[a * 33 + a];
            float v12 = Gsh[a * 33 + b];
            float v22 = Gsh[b * 33 + b];
            float g = (v22 - v12) / (v11 + v22 - 2.0f * v12 + EPSF);
            float c = v22 + g * (v12 - v22);
            float gamma = (v12 >= v22) ? 0.0f : g;
            float cost  = (v12 >= v22) ? v22 : c;
            if (v12 >= v11) { gamma = 1.0f; cost = v11; }
            int enc = a * NT + b;
            if (cost < bestCost) { bestCost = cost; bestEnc = enc; bestGamma = gamma; }
        }
    }
#pragma unroll
    for (int m = 1; m < 64; m <<= 1) {
        float oc = __shfl_xor(bestCost, m);
        int   oe = __shfl_xor(bestEnc, m);
        float og = __shfl_xor(bestGamma, m);
        if (oc < bestCost || (oc == bestCost && oe < bestEnc)) {
            bestCost = oc; bestEnc = oe; bestGamma = og;
        }
    }
    const int bi = bestEnc >> 5, bj = bestEnc & 31;

    float sol = 0.0f;                      // mirrored across halves
    if (e == bi) sol = bestGamma;
    if (e == bj) sol = 1.0f - bestGamma;

    for (int it = 0; it < 250; it++) {
        float Gsol = matvec(sol);          // exact (no recurrence: r4's 2.4e-4 was from it)

        // ---- next_point ----
        float grad = -Gsol;
        float proj = grad - bsum32u(grad) * 0.03125f;

        float tm1 = (proj < 0.0f) ? (-sol / proj) : INFINITY;
        float tm2 = (proj > 0.0f) ? ((1.0f - sol) / proj) : INFINITY;
        float m1 = bmin32u((tm1 > 1e-7f) ? tm1 : INFINITY);
        float m2 = bmin32u((tm2 > 1e-7f) ? tm2 : INFINITY);
        float t = __builtin_isinf(m1) ? 1.0f : m1;
        t = fminf(t, m2);
        float nxt = fmaf(proj, t, sol);

        // ---- simplex projection via half-split rank-select ----
        int nb = __float_as_int(nxt);
        unsigned u = (unsigned)nb ^ ((nb < 0) ? 0xFFFFFFFFu : 0x80000000u);

        int rank = 0;
        float S = 0.0f;
        const int dtie = e - 16 * h;       // j < e  <=>  s < dtie (j = s+16h)
#pragma unroll
        for (int s = 0; s < 16; s++) {
            float xj = __shfl(nxt, 16 * h + s);     // element j = s+16h
            int nbj = __float_as_int(xj);
            unsigned uj = (unsigned)nbj ^ ((nbj < 0) ? 0xFFFFFFFFu : 0x80000000u);
            bool gt = (uj > u) || ((uj == u) && (s < dtie));
            rank += gt ? 1 : 0;
            S += gt ? xj : 0.0f;
        }
        rank += __shfl_xor(rank, 32);      // int add: commutative, mirror-safe
        S += __shfl_xor(S, 32);            // fp add of 2: commutative bitwise

        float total = bsum32u(nxt);

        float cand = (S - 1.0f) / (float)rank;   // rank==0 -> -inf, cond false
        bool cond = (rank >= 1) && (cand > nxt);
        float rmin = bmin32u(cond ? (float)rank : INFINITY);
        unsigned long long msk = __ballot(cond && ((float)rank == rmin));
        int src = (int)__ffsll(msk) - 1;         // -1 iff msk==0 (guarded below)
        float tmax = (msk == 0ull)
                   ? (total - 1.0f) * 0.03125f
                   : rdlane(cand, src);
        float newp = fmaxf(nxt - tmax, 0.0f);    // mirrored (no upper zeroing)

        float Gn = matvec(newp);

        float z = (h == 0) ? (sol * Gsol) : (newp * Gn);
        z += dpp0<0x111>(z);
        z += dpp0<0x112>(z);
        z += dpp0<0x114>(z);
        z += dpp0<0x118>(z);
        float v11 = rdlane(z, 15) + rdlane(z, 31);
        float v22 = rdlane(z, 47) + rdlane(z, 63);
        float v12 = bsum32u(sol * Gn);

        float g = (v22 - v12) / (v11 + v22 - 2.0f * v12 + EPSF);
        float gamma = (v12 >= v22) ? 0.0f : g;
        gamma = (v12 >= v11) ? 1.0f : gamma;

        float new_sol = gamma * sol + (1.0f - gamma) * newp;
        float diff = bsum32u(fabsf(new_sol - sol));
        if (diff < 1e-6f) break;   // freeze: output the OLD sol (ref semantics)
        sol = new_sol;
    }
    if (lane < NT) out[lane] = sol;
}

extern "C" void kernel_launch(void* const* d_in, const int* in_sizes, int n_in,
                              void* d_out, int out_size, void* d_ws, size_t ws_size,
                              hipStream_t stream) {
    const float* vecs = (const float*)d_in[0];
    float* out = (float*)d_out;
    double* Gd = (double*)d_ws;          // 1024 doubles = 8 KB
    const int D = in_sizes[0] / NT;      // 2097152

    hipMemsetAsync(Gd, 0, NT * NT * sizeof(double), stream);

    const int cols_per_block = WAVES_PB * TILES_PW * TILE_COLS;  // 2048
    const int grid = D / cols_per_block;                          // 1024
    gram_kernel<<<grid, GR_THREADS, 0, stream>>>(vecs, Gd, D);
    solver_kernel<<<1, 64, 0, stream>>>(Gd, out);

    // ==== r8 ATTRIBUTION PROBE (one round only; removed next round) ====
    // Duplicate gram into scratch, reading a COLD 256 MiB workspace region
    // (poison fill's tail [768M,1G) owns L3, so [512M,768M) is L3-cold like
    // the real gram's input). dur_us_total - 410 = G_gram, exactly.
    // Real pipeline above is untouched; probe output is never read.
    if (ws_size >= ((size_t)768 << 20)) {
        double* Gd2 = (double*)((char*)d_ws + 8192);
        const float* src2 = (const float*)((char*)d_ws + ((size_t)512 << 20));
        gram_kernel<<<grid, GR_THREADS, 0, stream>>>(src2, Gd2, D);
    } else {
        // fallback: probe on vecs (L3-warm bias -> G lower bound)
        double* Gd2 = (double*)((char*)d_ws + 8192);
        gram_kernel<<<grid, GR_THREADS, 0, stream>>>(vecs, Gd2, D);
    }
}

// Round 7
// 412.232 us; speedup vs baseline: 1.1961x; 1.1961x over previous
//
#include <hip/hip_runtime.h>

#define NT 32
#define EPSF 1e-8f

// ================= Gram kernel =================
// BYTE-IDENTICAL to r7/r8 (r8 probe measured gram = 83us cold; floors:
// HBM 43us, LDS-pipe 46us, FMA-issue 27us -> 1.8x over max-floor).
// Next gram lever (queued): 16x8 patch halves ds_read per FMA.
#define TILE_COLS 64
#define GR_THREADS 256
#define WAVES_PB 4
#define TILES_PW 8    // cols/wave = 512, cols/block = 2048 -> grid = 1024

__global__ __launch_bounds__(GR_THREADS, 1)
void gram_kernel(const float* __restrict__ vecs, double* __restrict__ Gd, int D)
{
    __shared__ __align__(16) float tile[WAVES_PB][TILE_COLS * 32];
    __shared__ float Gpart[NT * NT];

    const int tid  = threadIdx.x;
    const int wave = tid >> 6;
    const int lane = tid & 63;

    for (int e = tid; e < NT * NT; e += GR_THREADS) Gpart[e] = 0.0f;
    __syncthreads();

    float* my = tile[wave];
    const int swz = lane & 7;

    const int cj = lane >> 4;        // column subgroup 0..3
    const int pi = (lane >> 2) & 3;  // patch rows 8*pi..
    const int pk = lane & 3;         // patch cols 8*pk..

    float acc[8][8];
#pragma unroll
    for (int r = 0; r < 8; r++)
#pragma unroll
        for (int c = 0; c < 8; c++) acc[r][c] = 0.0f;

    const unsigned base0 = (unsigned)blockIdx.x * (WAVES_PB * TILES_PW * TILE_COLS)
                         + (unsigned)wave * (TILES_PW * TILE_COLS) + (unsigned)lane;

    // prefetch tile 0 (SGPR row bases + one 32-bit lane offset)
    float pre[32];
#pragma unroll
    for (int r = 0; r < 32; r++)
        pre[r] = (vecs + (size_t)r * (size_t)D)[base0];

    for (int t = 0; t < TILES_PW; t++) {
        // stage tile t from pre[]: 8 swizzled b128 writes
#pragma unroll
        for (int g = 0; g < 8; g++) {
            float4 w = make_float4(pre[4 * g + 0], pre[4 * g + 1],
                                   pre[4 * g + 2], pre[4 * g + 3]);
            *(float4*)(my + lane * 32 + ((g ^ swz) << 2)) = w;
        }
        // prefetch tile t+1; loads fly during the compute below
        if (t + 1 < TILES_PW) {
            const unsigned off = base0 + (unsigned)(t + 1) * TILE_COLS;
#pragma unroll
            for (int r = 0; r < 32; r++)
                pre[r] = (vecs + (size_t)r * (size_t)D)[off];
        }
        // r7 scheduling fence (measured neutral; kept, harmless)
        asm volatile("" ::: "memory");
        // compute on tile t (per-wave DS ops are in-order; no barrier needed)
#pragma unroll
        for (int jt = 0; jt < 16; jt++) {
            const int j = (jt << 2) + cj;
            const float* col = my + j * 32;
            const int js = j & 7;
            const float4 a0 = *(const float4*)(col + (((2 * pi) ^ js) << 2));
            const float4 a1 = *(const float4*)(col + (((2 * pi + 1) ^ js) << 2));
            const float4 b0 = *(const float4*)(col + (((2 * pk) ^ js) << 2));
            const float4 b1 = *(const float4*)(col + (((2 * pk + 1) ^ js) << 2));
            const float a[8] = {a0.x, a0.y, a0.z, a0.w, a1.x, a1.y, a1.z, a1.w};
            const float b[8] = {b0.x, b0.y, b0.z, b0.w, b1.x, b1.y, b1.z, b1.w};
#pragma unroll
            for (int r = 0; r < 8; r++)
#pragma unroll
                for (int c = 0; c < 8; c++)
                    acc[r][c] = fmaf(a[r], b[c], acc[r][c]);
        }
    }

    // fold the cj column-split (lanes sharing lane&15 share a patch)
#pragma unroll
    for (int r = 0; r < 8; r++)
#pragma unroll
        for (int c = 0; c < 8; c++) {
            float v = acc[r][c];
            v += __shfl_xor(v, 16);
            v += __shfl_xor(v, 32);
            if (lane < 16)
                atomicAdd(&Gpart[(8 * pi + r) * NT + (8 * pk + c)], v);
        }
    __syncthreads();
    for (int e = tid; e < NT * NT; e += GR_THREADS)
        atomicAdd(&Gd[e], (double)Gpart[e]);
}

// ================= Solver kernel =================
// r8 attribution: solver ~ 155us (~1490 cy/iter) -- the dominant optimizable
// term. Single wave => every VALU inst costs 2cy issue (no co-resident wave)
// and all DPP/readlane/lgkm latencies are exposed.
// r9 diet (every FP value bit-preserved; only commutativity-safe rewrites):
//  (1) row_bcast15 (DPP 0x142) tree tails: one DPP-op + ONE readlane(31)
//      replaces {readlane15, readlane31, mov, add/fmin}. lane31 computes
//      row1(+/min)row0 vs old row0(+/min)row1 -- commutative, bitwise same.
//      (row2 lanes get lane31 pollution -- never read; lane63's DPP source is
//      lane47's PRE-op value, so upper-half results stay exact.)
//  (2) tm1/tm2 min-trees merged into ONE half-split tree (v11/v22 pattern):
//      mirror symmetry => lower-half tree == bmin32u(tm1), upper == (tm2).
//  (3) rank loop shuffles the precomputed key u (1 bpermute) instead of
//      recomputing it from xj (3 VALU) per step.
//  (4) deferred convergence check: the diff tree is issued at iteration end,
//      its readlane+branch consumed AFTER the next matvec issues (tree drain
//      hides under matvec DS ops). Same diff values, same threshold, same
//      freeze-old-sol semantics; post-loop check covers body #250.
template<int CTRL>
__device__ __forceinline__ float dpp0(float x) {  // invalid source lanes -> 0
    return __int_as_float(__builtin_amdgcn_update_dpp(
        0, __float_as_int(x), CTRL, 0xF, 0xF, true));
}
template<int CTRL>
__device__ __forceinline__ float dppk(float oldv, float x) {  // invalid -> oldv
    return __int_as_float(__builtin_amdgcn_update_dpp(
        __float_as_int(oldv), __float_as_int(x), CTRL, 0xF, 0xF, false));
}
__device__ __forceinline__ float rdlane(float x, int l) {
    return __int_as_float(__builtin_amdgcn_readlane(__float_as_int(x), l));
}

// 32-element sum of mirrored data; result uniform via one readlane(31).
// lane31 ends with row1sum + row0sum (== old row0+row1, commutative).
__device__ __forceinline__ float bsum32u(float v) {
    v += dpp0<0x111>(v);
    v += dpp0<0x112>(v);
    v += dpp0<0x114>(v);
    v += dpp0<0x118>(v);
    v += dpp0<0x142>(v);     // row_bcast15: lane31 += lane15
    return rdlane(v, 31);
}
__device__ __forceinline__ float bmin32u(float v) {
    v = fminf(v, dppk<0x111>(v, v));
    v = fminf(v, dppk<0x112>(v, v));
    v = fminf(v, dppk<0x114>(v, v));
    v = fminf(v, dppk<0x118>(v, v));
    v = fminf(v, dppk<0x142>(v, v)); // lane31 = fmin(row1, row0)
    return rdlane(v, 31);
}

__global__ __launch_bounds__(64)
void solver_kernel(const double* __restrict__ Gd, float* __restrict__ out)
{
    __shared__ float Gsh[NT * 33];

    const int lane = threadIdx.x;
    const int e = lane & 31;      // element owned (mirrored halves)
    const int h = lane >> 5;      // half: covers k/j in [16h, 16h+16)

    for (int t2 = 0; t2 < 16; t2++) {
        int idx = t2 * 64 + lane;
        Gsh[(idx >> 5) * 33 + (idx & 31)] = (float)Gd[idx];
    }
    __syncthreads();

    // lane holds G[e][16h + k], k = 0..15
    float Grow[16];
#pragma unroll
    for (int k = 0; k < 16; k++)
        Grow[k] = Gsh[e * 33 + 16 * h + k];

    // half-split matvec (verified r6): order identical to the Tvec path.
    auto matvec = [&](float x) -> float {
        float a0 = 0.0f, a1 = 0.0f;
#pragma unroll
        for (int s = 0; s < 16; s += 2) {
            a0 = fmaf(Grow[s + 0], __shfl(x, 16 * h + s + 0), a0);
            a1 = fmaf(Grow[s + 1], __shfl(x, 16 * h + s + 1), a1);
        }
        float half = a0 + a1;
        return half + __shfl_xor(half, 32);
    };

    // ---- planar init: argmin over all 496 (a<b) pairs ----
    float bestCost = INFINITY, bestGamma = 0.0f;
    int bestEnc = 0x7FFFFFFF;
    for (int a = 0; a < NT - 1; a++) {
        int b = a + 1 + lane;
        if (b < NT) {
            float v11 = Gsh[a * 33 + a];
            float v12 = Gsh[a * 33 + b];
            float v22 = Gsh[b * 33 + b];
            float g = (v22 - v12) / (v11 + v22 - 2.0f * v12 + EPSF);
            float c = v22 + g * (v12 - v22);
            float gamma = (v12 >= v22) ? 0.0f : g;
            float cost  = (v12 >= v22) ? v22 : c;
            if (v12 >= v11) { gamma = 1.0f; cost = v11; }
            int enc = a * NT + b;
            if (cost < bestCost) { bestCost = cost; bestEnc = enc; bestGamma = gamma; }
        }
    }
#pragma unroll
    for (int m = 1; m < 64; m <<= 1) {
        float oc = __shfl_xor(bestCost, m);
        int   oe = __shfl_xor(bestEnc, m);
        float og = __shfl_xor(bestGamma, m);
        if (oc < bestCost || (oc == bestCost && oe < bestEnc)) {
            bestCost = oc; bestEnc = oe; bestGamma = og;
        }
    }
    const int bi = bestEnc >> 5, bj = bestEnc & 31;

    float sol = 0.0f;                      // mirrored across halves
    if (e == bi) sol = bestGamma;
    if (e == bj) sol = 1.0f - bestGamma;

    float prev = sol;
    float dv = INFINITY;                   // pending diff tree (valid it>0)

    for (int it = 0; it < 250; it++) {
        float Gsol = matvec(sol);          // issue first: hides dv tree drain

        if (it > 0) {                      // deferred convergence check
            float diff = rdlane(dv, 31);
            if (diff < 1e-6f) { sol = prev; goto frozen; }
        }
        {
        // ---- next_point ----
        float grad = -Gsol;
        float proj = grad - bsum32u(grad) * 0.03125f;

        float tm1 = (proj < 0.0f) ? (-sol / proj) : INFINITY;
        float tm2 = (proj > 0.0f) ? ((1.0f - sol) / proj) : INFINITY;
        // merged half-split min tree: lower half == bmin32u(tm1),
        // upper half == bmin32u(tm2) (mirror symmetry; commutative tails).
        float zt = (h == 0) ? ((tm1 > 1e-7f) ? tm1 : INFINITY)
                            : ((tm2 > 1e-7f) ? tm2 : INFINITY);
        zt = fminf(zt, dppk<0x111>(zt, zt));
        zt = fminf(zt, dppk<0x112>(zt, zt));
        zt = fminf(zt, dppk<0x114>(zt, zt));
        zt = fminf(zt, dppk<0x118>(zt, zt));
        zt = fminf(zt, dppk<0x142>(zt, zt));
        float m1 = rdlane(zt, 31);
        float m2 = rdlane(zt, 63);
        float t = __builtin_isinf(m1) ? 1.0f : m1;
        t = fminf(t, m2);
        float nxt = fmaf(proj, t, sol);

        // ---- simplex projection via half-split rank-select ----
        int nb = __float_as_int(nxt);
        unsigned u = (unsigned)nb ^ ((nb < 0) ? 0xFFFFFFFFu : 0x80000000u);

        int rank = 0;
        float S = 0.0f;
        const int dtie = e - 16 * h;       // j < e  <=>  s < dtie (j = s+16h)
#pragma unroll
        for (int s = 0; s < 16; s++) {
            float    xj = __shfl(nxt, 16 * h + s);        // element j = s+16h
            unsigned uj = (unsigned)__shfl((int)u, 16 * h + s);  // its key
            bool gt = (uj > u) || ((uj == u) && (s < dtie));
            rank += gt ? 1 : 0;
            S += gt ? xj : 0.0f;
        }
        rank += __shfl_xor(rank, 32);      // int add: commutative, mirror-safe
        S += __shfl_xor(S, 32);            // fp add of 2: commutative bitwise

        float total = bsum32u(nxt);

        float cand = (S - 1.0f) / (float)rank;   // rank==0 -> -inf, cond false
        bool cond = (rank >= 1) && (cand > nxt);
        float rmin = bmin32u(cond ? (float)rank : INFINITY);
        unsigned long long msk = __ballot(cond && ((float)rank == rmin));
        int src = (int)__ffsll(msk) - 1;         // -1 iff msk==0 (guarded below)
        float tmax = (msk == 0ull)
                   ? (total - 1.0f) * 0.03125f
                   : rdlane(cand, src);
        float newp = fmaxf(nxt - tmax, 0.0f);    // mirrored (no upper zeroing)

        float Gn = matvec(newp);

        // v11 (lower: sol*Gsol) and v22 (upper: newp*Gn) in one tree;
        // bcast15 tails are commutative-equal to the old readlane pairs.
        float z = (h == 0) ? (sol * Gsol) : (newp * Gn);
        z += dpp0<0x111>(z);
        z += dpp0<0x112>(z);
        z += dpp0<0x114>(z);
        z += dpp0<0x118>(z);
        z += dpp0<0x142>(z);
        float v11 = rdlane(z, 31);
        float v22 = rdlane(z, 63);
        float v12 = bsum32u(sol * Gn);

        float g = (v22 - v12) / (v11 + v22 - 2.0f * v12 + EPSF);
        float gamma = (v12 >= v22) ? 0.0f : g;
        gamma = (v12 >= v11) ? 1.0f : gamma;

        float new_sol = gamma * sol + (1.0f - gamma) * newp;

        // issue the diff tree; its result is consumed next iteration (or in
        // the post-loop check). Values identical to the old in-loop check.
        float dval = fabsf(new_sol - sol);
        prev = sol;
        sol = new_sol;
        dv = dval;
        dv += dpp0<0x111>(dv);
        dv += dpp0<0x112>(dv);
        dv += dpp0<0x114>(dv);
        dv += dpp0<0x118>(dv);
        dv += dpp0<0x142>(dv);
        }
    }
    // body #250's convergence check (ref freezes to old sol if it converged)
    if (rdlane(dv, 31) < 1e-6f) sol = prev;
frozen:
    if (lane < NT) out[lane] = sol;
}

extern "C" void kernel_launch(void* const* d_in, const int* in_sizes, int n_in,
                              void* d_out, int out_size, void* d_ws, size_t ws_size,
                              hipStream_t stream) {
    const float* vecs = (const float*)d_in[0];
    float* out = (float*)d_out;
    double* Gd = (double*)d_ws;          // 1024 doubles = 8 KB
    const int D = in_sizes[0] / NT;      // 2097152

    hipMemsetAsync(Gd, 0, NT * NT * sizeof(double), stream);

    const int cols_per_block = WAVES_PB * TILES_PW * TILE_COLS;  // 2048
    const int grid = D / cols_per_block;                          // 1024
    gram_kernel<<<grid, GR_THREADS, 0, stream>>>(vecs, Gd, D);
    solver_kernel<<<1, 64, 0, stream>>>(Gd, out);
}

// Round 8
// 411.445 us; speedup vs baseline: 1.1984x; 1.0019x over previous
//
#include <hip/hip_runtime.h>

#define NT 32
#define EPSF 1e-8f

// ================= Gram kernel =================
// BYTE-IDENTICAL to r7/r8/r9 (r8 probe: gram = 83us cold; floors: HBM 43us,
// LDS-pipe 46us, FMA-issue 27us). Queued lever: 16x8 patch, DS/FMA rebalance.
#define TILE_COLS 64
#define GR_THREADS 256
#define WAVES_PB 4
#define TILES_PW 8    // cols/wave = 512, cols/block = 2048 -> grid = 1024

__global__ __launch_bounds__(GR_THREADS, 1)
void gram_kernel(const float* __restrict__ vecs, double* __restrict__ Gd, int D)
{
    __shared__ __align__(16) float tile[WAVES_PB][TILE_COLS * 32];
    __shared__ float Gpart[NT * NT];

    const int tid  = threadIdx.x;
    const int wave = tid >> 6;
    const int lane = tid & 63;

    for (int e = tid; e < NT * NT; e += GR_THREADS) Gpart[e] = 0.0f;
    __syncthreads();

    float* my = tile[wave];
    const int swz = lane & 7;

    const int cj = lane >> 4;        // column subgroup 0..3
    const int pi = (lane >> 2) & 3;  // patch rows 8*pi..
    const int pk = lane & 3;         // patch cols 8*pk..

    float acc[8][8];
#pragma unroll
    for (int r = 0; r < 8; r++)
#pragma unroll
        for (int c = 0; c < 8; c++) acc[r][c] = 0.0f;

    const unsigned base0 = (unsigned)blockIdx.x * (WAVES_PB * TILES_PW * TILE_COLS)
                         + (unsigned)wave * (TILES_PW * TILE_COLS) + (unsigned)lane;

    // prefetch tile 0 (SGPR row bases + one 32-bit lane offset)
    float pre[32];
#pragma unroll
    for (int r = 0; r < 32; r++)
        pre[r] = (vecs + (size_t)r * (size_t)D)[base0];

    for (int t = 0; t < TILES_PW; t++) {
        // stage tile t from pre[]: 8 swizzled b128 writes
#pragma unroll
        for (int g = 0; g < 8; g++) {
            float4 w = make_float4(pre[4 * g + 0], pre[4 * g + 1],
                                   pre[4 * g + 2], pre[4 * g + 3]);
            *(float4*)(my + lane * 32 + ((g ^ swz) << 2)) = w;
        }
        // prefetch tile t+1; loads fly during the compute below
        if (t + 1 < TILES_PW) {
            const unsigned off = base0 + (unsigned)(t + 1) * TILE_COLS;
#pragma unroll
            for (int r = 0; r < 32; r++)
                pre[r] = (vecs + (size_t)r * (size_t)D)[off];
        }
        // r7 scheduling fence (measured neutral; kept, harmless)
        asm volatile("" ::: "memory");
        // compute on tile t (per-wave DS ops are in-order; no barrier needed)
#pragma unroll
        for (int jt = 0; jt < 16; jt++) {
            const int j = (jt << 2) + cj;
            const float* col = my + j * 32;
            const int js = j & 7;
            const float4 a0 = *(const float4*)(col + (((2 * pi) ^ js) << 2));
            const float4 a1 = *(const float4*)(col + (((2 * pi + 1) ^ js) << 2));
            const float4 b0 = *(const float4*)(col + (((2 * pk) ^ js) << 2));
            const float4 b1 = *(const float4*)(col + (((2 * pk + 1) ^ js) << 2));
            const float a[8] = {a0.x, a0.y, a0.z, a0.w, a1.x, a1.y, a1.z, a1.w};
            const float b[8] = {b0.x, b0.y, b0.z, b0.w, b1.x, b1.y, b1.z, b1.w};
#pragma unroll
            for (int r = 0; r < 8; r++)
#pragma unroll
                for (int c = 0; c < 8; c++)
                    acc[r][c] = fmaf(a[r], b[c], acc[r][c]);
        }
    }

    // fold the cj column-split (lanes sharing lane&15 share a patch)
#pragma unroll
    for (int r = 0; r < 8; r++)
#pragma unroll
        for (int c = 0; c < 8; c++) {
            float v = acc[r][c];
            v += __shfl_xor(v, 16);
            v += __shfl_xor(v, 32);
            if (lane < 16)
                atomicAdd(&Gpart[(8 * pi + r) * NT + (8 * pk + c)], v);
        }
    __syncthreads();
    for (int e = tid; e < NT * NT; e += GR_THREADS)
        atomicAdd(&Gd[e], (double)Gpart[e]);
}

// ================= Solver kernel =================
// r10 model (after 3 nulls): the solver is DS-PIPE-bound, not VALU-bound.
// r6 structure had ~68 ds_bpermute/iter (2 matvecs x16 + rank x16(xj)+... ),
// each a full LDS round-trip with nothing to hide it (single wave). r9's
// VALU diet moved nothing (+2.2us) because DS was untouched.
// r10: every 16-element broadcast becomes {1 ds_write_b32 (2-way alias, free)
// + 4 uniform-addr ds_read_b128} on a mirrored 64-float LDS buffer:
//   - lanes h=0 read floats [0..15]  (elements 0..15, same addr = broadcast)
//   - lanes h=1 read floats [48..63] (elements 16..31; banks 16-19 vs 0-3,
//     disjoint from h=0's -> conflict-free)
// DS ops/iter: 68 -> ~19 (3 writes + 12 b128 reads + 4 xor32 combines).
// Everything else (FMA order, trees, uj bit-ops, convergence) reverted to the
// VERIFIED r6 solver (409.99us, absmax 0.0) -> values bit-identical; the xj
// read from LDS equals the xj the bpermute fetched.
template<int CTRL>
__device__ __forceinline__ float dpp0(float x) {  // invalid source lanes -> 0
    return __int_as_float(__builtin_amdgcn_update_dpp(
        0, __float_as_int(x), CTRL, 0xF, 0xF, true));
}
template<int CTRL>
__device__ __forceinline__ float dppk(float oldv, float x) {  // invalid -> oldv
    return __int_as_float(__builtin_amdgcn_update_dpp(
        __float_as_int(oldv), __float_as_int(x), CTRL, 0xF, 0xF, false));
}
__device__ __forceinline__ float rdlane(float x, int l) {
    return __int_as_float(__builtin_amdgcn_readlane(__float_as_int(x), l));
}

// sum over lanes 0..31, uniform (row_shr chain leaves sums at 15 & 31)
__device__ __forceinline__ float bsum32u(float v) {
    v += dpp0<0x111>(v);
    v += dpp0<0x112>(v);
    v += dpp0<0x114>(v);
    v += dpp0<0x118>(v);
    return rdlane(v, 15) + rdlane(v, 31);
}
__device__ __forceinline__ float bmin32u(float v) {
    v = fminf(v, dppk<0x111>(v, v));
    v = fminf(v, dppk<0x112>(v, v));
    v = fminf(v, dppk<0x114>(v, v));
    v = fminf(v, dppk<0x118>(v, v));
    return fminf(rdlane(v, 15), rdlane(v, 31));
}

__global__ __launch_bounds__(64)
void solver_kernel(const double* __restrict__ Gd, float* __restrict__ out)
{
    __shared__ float Gsh[NT * 33];
    __shared__ __align__(16) float xb0[64];  // sol broadcast buffer
    __shared__ __align__(16) float xb1[64];  // nxt broadcast buffer
    __shared__ __align__(16) float xb2[64];  // newp broadcast buffer

    const int lane = threadIdx.x;
    const int e = lane & 31;      // element owned (mirrored halves)
    const int h = lane >> 5;      // half: covers k/j in [16h, 16h+16)

    for (int t2 = 0; t2 < 16; t2++) {
        int idx = t2 * 64 + lane;
        Gsh[(idx >> 5) * 33 + (idx & 31)] = (float)Gd[idx];
    }
    __syncthreads();

    // lane holds G[e][16h + k], k = 0..15
    float Grow[16];
#pragma unroll
    for (int k = 0; k < 16; k++)
        Grow[k] = Gsh[e * 33 + 16 * h + k];

    // per-half b128 read bases: h=0 -> floats[0..15], h=1 -> floats[48..63]
    const int hb = h * 48;
    const float4* xr0 = (const float4*)(xb0 + hb);
    const float4* xr1 = (const float4*)(xb1 + hb);
    const float4* xr2 = (const float4*)(xb2 + hb);

    // half-split matvec via 4 uniform ds_read_b128 (values & FMA order
    // identical to the verified bpermute version).
    auto mv = [&](const float4* xr) -> float {
        const float4 q0 = xr[0], q1 = xr[1], q2 = xr[2], q3 = xr[3];
        const float xv[16] = {q0.x, q0.y, q0.z, q0.w, q1.x, q1.y, q1.z, q1.w,
                              q2.x, q2.y, q2.z, q2.w, q3.x, q3.y, q3.z, q3.w};
        float a0 = 0.0f, a1 = 0.0f;
#pragma unroll
        for (int s = 0; s < 16; s += 2) {
            a0 = fmaf(Grow[s + 0], xv[s + 0], a0);
            a1 = fmaf(Grow[s + 1], xv[s + 1], a1);
        }
        float half = a0 + a1;
        return half + __shfl_xor(half, 32);
    };

    // ---- planar init: argmin over all 496 (a<b) pairs ----
    float bestCost = INFINITY, bestGamma = 0.0f;
    int bestEnc = 0x7FFFFFFF;
    for (int a = 0; a < NT - 1; a++) {
        int b = a + 1 + lane;
        if (b < NT) {
            float v11 = Gsh[a * 33 + a];
            float v12 = Gsh[a * 33 + b];
            float v22 = Gsh[b * 33 + b];
            float g = (v22 - v12) / (v11 + v22 - 2.0f * v12 + EPSF);
            float c = v22 + g * (v12 - v22);
            float gamma = (v12 >= v22) ? 0.0f : g;
            float cost  = (v12 >= v22) ? v22 : c;
            if (v12 >= v11) { gamma = 1.0f; cost = v11; }
            int enc = a * NT + b;
            if (cost < bestCost) { bestCost = cost; bestEnc = enc; bestGamma = gamma; }
        }
    }
#pragma unroll
    for (int m = 1; m < 64; m <<= 1) {
        float oc = __shfl_xor(bestCost, m);
        int   oe = __shfl_xor(bestEnc, m);
        float og = __shfl_xor(bestGamma, m);
        if (oc < bestCost || (oc == bestCost && oe < bestEnc)) {
            bestCost = oc; bestEnc = oe; bestGamma = og;
        }
    }
    const int bi = bestEnc >> 5, bj = bestEnc & 31;

    float sol = 0.0f;                      // mirrored across halves
    if (e == bi) sol = bestGamma;
    if (e == bj) sol = 1.0f - bestGamma;

    xb0[lane] = sol;                       // stage sol for iteration 0

    for (int it = 0; it < 250; it++) {
        float Gsol = mv(xr0);              // reads xb0 (written prev iter)

        // ---- next_point ----
        float grad = -Gsol;
        float proj = grad - bsum32u(grad) * 0.03125f;

        float tm1 = (proj < 0.0f) ? (-sol / proj) : INFINITY;
        float tm2 = (proj > 0.0f) ? ((1.0f - sol) / proj) : INFINITY;
        float m1 = bmin32u((tm1 > 1e-7f) ? tm1 : INFINITY);
        float m2 = bmin32u((tm2 > 1e-7f) ? tm2 : INFINITY);
        float t = __builtin_isinf(m1) ? 1.0f : m1;
        t = fminf(t, m2);
        float nxt = fmaf(proj, t, sol);

        // ---- simplex projection via half-split rank-select ----
        int nb = __float_as_int(nxt);
        unsigned u = (unsigned)nb ^ ((nb < 0) ? 0xFFFFFFFFu : 0x80000000u);

        xb1[lane] = nxt;                   // stage nxt; in-order DS per wave
        const float4 r0 = xr1[0], r1 = xr1[1], r2 = xr1[2], r3 = xr1[3];
        const float xj16[16] = {r0.x, r0.y, r0.z, r0.w, r1.x, r1.y, r1.z, r1.w,
                                r2.x, r2.y, r2.z, r2.w, r3.x, r3.y, r3.z, r3.w};

        int rank = 0;
        float S = 0.0f;
        const int dtie = e - 16 * h;       // j < e  <=>  s < dtie (j = s+16h)
#pragma unroll
        for (int s = 0; s < 16; s++) {
            float xj = xj16[s];
            int nbj = __float_as_int(xj);
            unsigned uj = (unsigned)nbj ^ ((nbj < 0) ? 0xFFFFFFFFu : 0x80000000u);
            bool gt = (uj > u) || ((uj == u) && (s < dtie));
            rank += gt ? 1 : 0;
            S += gt ? xj : 0.0f;
        }
        rank += __shfl_xor(rank, 32);      // int add: commutative, mirror-safe
        S += __shfl_xor(S, 32);            // fp add of 2: commutative bitwise

        float total = bsum32u(nxt);

        float cand = (S - 1.0f) / (float)rank;   // rank==0 -> -inf, cond false
        bool cond = (rank >= 1) && (cand > nxt);
        float rmin = bmin32u(cond ? (float)rank : INFINITY);
        unsigned long long msk = __ballot(cond && ((float)rank == rmin));
        int src = (int)__ffsll(msk) - 1;         // -1 iff msk==0 (guarded below)
        float tmax = (msk == 0ull)
                   ? (total - 1.0f) * 0.03125f
                   : rdlane(cand, src);
        float newp = fmaxf(nxt - tmax, 0.0f);    // mirrored (no upper zeroing)

        xb2[lane] = newp;                  // stage newp
        float Gn = mv(xr2);

        // v11/v22 share one element-ordered reduction chain (verified r6)
        float z = (h == 0) ? (sol * Gsol) : (newp * Gn);
        z += dpp0<0x111>(z);
        z += dpp0<0x112>(z);
        z += dpp0<0x114>(z);
        z += dpp0<0x118>(z);
        float v11 = rdlane(z, 15) + rdlane(z, 31);
        float v22 = rdlane(z, 47) + rdlane(z, 63);
        float v12 = bsum32u(sol * Gn);

        float g = (v22 - v12) / (v11 + v22 - 2.0f * v12 + EPSF);
        float gamma = (v12 >= v22) ? 0.0f : g;
        gamma = (v12 >= v11) ? 1.0f : gamma;

        float new_sol = gamma * sol + (1.0f - gamma) * newp;
        float diff = bsum32u(fabsf(new_sol - sol));
        if (diff < 1e-6f) break;   // freeze: output the OLD sol (ref semantics)
        sol = new_sol;
        xb0[lane] = sol;           // stage for next iteration's matvec
    }
    if (lane < NT) out[lane] = sol;
}

extern "C" void kernel_launch(void* const* d_in, const int* in_sizes, int n_in,
                              void* d_out, int out_size, void* d_ws, size_t ws_size,
                              hipStream_t stream) {
    const float* vecs = (const float*)d_in[0];
    float* out = (float*)d_out;
    double* Gd = (double*)d_ws;          // 1024 doubles = 8 KB
    const int D = in_sizes[0] / NT;      // 2097152

    hipMemsetAsync(Gd, 0, NT * NT * sizeof(double), stream);

    const int cols_per_block = WAVES_PB * TILES_PW * TILE_COLS;  // 2048
    const int grid = D / cols_per_block;                          // 1024
    gram_kernel<<<grid, GR_THREADS, 0, stream>>>(vecs, Gd, D);
    solver_kernel<<<1, 64, 0, stream>>>(Gd, out);
}